// Round 1
// baseline (395.808 us; speedup 1.0000x reference)
//
#include <hip/hip_runtime.h>
#include <hip/hip_bf16.h>
#include <math.h>

// Problem constants (from reference)
#define VDIM 50000   // K (vocab / nodeNum)
#define BDIM 1024    // M (batch)
#define EDIM 256     // N (embedding)
#define LDIM 17      // Huffman path length

constexpr int BM = 128, BN = 128, BK = 32;
constexpr int KT_FULL = VDIM / BK;            // 1562 full k-tiles
constexpr int SPLITS  = 32;                   // interleaved split-K -> grid 512 = 2 blocks/CU
constexpr int TAILZ   = KT_FULL % SPLITS;     // 26: split owning the 16-col tail tile
constexpr int NBLK    = (EDIM / BN) * (BDIM / BM) * SPLITS;  // 512

typedef short bf16x8 __attribute__((ext_vector_type(8)));  // 8 bf16 (4 VGPRs)
typedef float f32x4  __attribute__((ext_vector_type(4)));

// async global->LDS, 16 B per lane; LDS dest = wave-uniform base + lane*16
__device__ __forceinline__ void async_f4(const float* g, float* l) {
    __builtin_amdgcn_global_load_lds(
        (const __attribute__((address_space(1))) void*)g,
        (__attribute__((address_space(3))) void*)l, 16, 0, 0);
}

// 8 consecutive fp32 -> bf16 hi fragment + bf16 lo fragment.
// hi = truncate(f); lo = truncate(f - hi); total error <= 2^-16 |f|.
__device__ __forceinline__ void split8(const float4 f0, const float4 f1, bf16x8& h, bf16x8& l) {
    const float f[8] = {f0.x, f0.y, f0.z, f0.w, f1.x, f1.y, f1.z, f1.w};
#pragma unroll
    for (int i = 0; i < 8; ++i) {
        const uint32_t u  = __float_as_uint(f[i]);
        h[i] = (short)(u >> 16);
        const float lo = f[i] - __uint_as_float(u & 0xFFFF0000u);
        l[i] = (short)(__float_as_uint(lo) >> 16);
    }
}

// emb_partial = x @ W^T via split-K atomics; bf16 split-3 (Ah*Bh + Ah*Bl + Al*Bh).
// Double-buffered LDS pipeline: loads for tile t+1 issued right after the barrier
// publishing tile t, so the next barrier's vmcnt(0) drain lands after ~1300 cyc of
// compute (> HBM latency) instead of immediately after issue.
// LDS holds raw fp32 tiles (global_load_lds, XOR-swizzled source columns:
// LDS[row][g*4..] = global[row][(g ^ (row&7))*4..]; no padding allowed).
//
// NEW (this round): 1-D grid + z-grouped XCD mapping. HW assigns XCD = wgid % 8;
// we decode blocks so all 16 blocks of a split z share one XCD -> the per-k-tile
// working set (128 KB X-rows + 32 KB W-rows) is fetched into ONE L2 and shared,
// instead of scattered across 4+ non-coherent XCD L2s. Pure index bijection.
__global__ __launch_bounds__(256) void gemm_split3(
    const float* __restrict__ X, const float* __restrict__ Wm, float* __restrict__ emb) {
    __shared__ __align__(16) float sA[2][BM * BK];   // 2 x 16 KB
    __shared__ __align__(16) float sB[2][BN * BK];   // 2 x 16 KB

    const int tid = threadIdx.x;

    // XCD-grouped decode: n%8 = XCD (dispatch round-robin). Each XCD r owns
    // z in {4r .. 4r+3}; within a z, 16 blocks = 2 (E tiles) x 8 (B tiles).
    const int n   = blockIdx.x;
    const int r   = n & 7;
    const int q   = n >> 3;                   // 0..63
    const int z   = (r << 2) + (q >> 4);      // split: tiles z, z+SPLITS, ...
    const int t16 = q & 15;
    const int bn0 = (t16 & 1) * BN;           // E offset
    const int bm0 = (t16 >> 1) * BM;          // B offset

    const int lane = tid & 63;
    const int wv   = tid >> 6;                // wave 0..3
    const int wm0  = (wv >> 1) * 64;          // wave tile origin
    const int wn0  = (wv & 1) * 64;
    const int lm   = lane & 15;               // fragment m/n index
    const int gk0  = (lane >> 4) * 2;         // first 4-float group of this lane's k-slice

    // staging geometry: each wave-instruction deposits 8 rows x 32 floats (1 KB)
    const int rsub   = lane >> 3;             // row within 8-row chunk; == row&7
    const int grp    = lane & 7;              // LDS 4-float group this lane fills
    const int coloff = ((grp ^ rsub) << 2);   // swizzled source column within tile
    const int rowS   = wv * 32 + rsub;        // + j*8, j=0..3

    f32x4 acc[4][4] = {};

    auto issue = [&](int kt, int pb) {
        const int k0 = kt * BK;
#pragma unroll
        for (int j = 0; j < 4; ++j) {
            const int row = rowS + j * 8;
            async_f4(X  + (size_t)(bm0 + row) * VDIM + k0 + coloff, &sA[pb][(wv * 32 + j * 8) * BK]);
            async_f4(Wm + (size_t)(bn0 + row) * VDIM + k0 + coloff, &sB[pb][(wv * 32 + j * 8) * BK]);
        }
    };

    auto compute = [&](int pb) {
        const float* A = sA[pb];
        const float* Bs = sB[pb];
        bf16x8 ah[4], al[4];
#pragma unroll
        for (int mi = 0; mi < 4; ++mi) {
            const int row = wm0 + mi * 16 + lm;
            const int s = row & 7;
            const float4 f0 = *reinterpret_cast<const float4*>(&A[row * BK + ((gk0 ^ s) << 2)]);
            const float4 f1 = *reinterpret_cast<const float4*>(&A[row * BK + (((gk0 + 1) ^ s) << 2)]);
            split8(f0, f1, ah[mi], al[mi]);
        }
#pragma unroll
        for (int ni = 0; ni < 4; ++ni) {
            const int row = wn0 + ni * 16 + lm;
            const int s = row & 7;
            const float4 f0 = *reinterpret_cast<const float4*>(&Bs[row * BK + ((gk0 ^ s) << 2)]);
            const float4 f1 = *reinterpret_cast<const float4*>(&Bs[row * BK + (((gk0 + 1) ^ s) << 2)]);
            bf16x8 bh, bl;
            split8(f0, f1, bh, bl);
            // T5: favor the MFMA-entering wave over the co-resident block's VALU burst
            __builtin_amdgcn_s_setprio(1);
#pragma unroll
            for (int mi = 0; mi < 4; ++mi) {
                acc[mi][ni] = __builtin_amdgcn_mfma_f32_16x16x32_bf16(ah[mi], bh, acc[mi][ni], 0, 0, 0);
                acc[mi][ni] = __builtin_amdgcn_mfma_f32_16x16x32_bf16(ah[mi], bl, acc[mi][ni], 0, 0, 0);
                acc[mi][ni] = __builtin_amdgcn_mfma_f32_16x16x32_bf16(al[mi], bh, acc[mi][ni], 0, 0, 0);
            }
            __builtin_amdgcn_s_setprio(0);
        }
    };

    // pipelined main loop over this split's tiles
    int pb = 0;
    issue(z, 0);                              // prologue: first tile into buf 0
    for (int kt = z + SPLITS; kt < KT_FULL; kt += SPLITS) {
        __syncthreads();                      // drains vmcnt -> buf pb ready; buf pb^1 free
        issue(kt, pb ^ 1);                    // prefetch next tile (in flight across compute)
        compute(pb);
        pb ^= 1;
    }
    __syncthreads();                          // last tile's loads drained
    compute(pb);

    if (z == TAILZ) {                         // tail tile kt=1562: cols 49984..49999 valid
        const int k0 = KT_FULL * BK;
#pragma unroll
        for (int j = 0; j < 4; ++j) {
            const int row = rowS + j * 8;
            float4 va = make_float4(0.f, 0.f, 0.f, 0.f), vb = va;
            if (coloff < 16) {                // groups beyond K-remainder stay zero
                va = *reinterpret_cast<const float4*>(X  + (size_t)(bm0 + row) * VDIM + k0 + coloff);
                vb = *reinterpret_cast<const float4*>(Wm + (size_t)(bn0 + row) * VDIM + k0 + coloff);
            }
            // same LDS bytes the async path would write: base + lane*16
            *reinterpret_cast<float4*>(&sA[pb ^ 1][row * BK + (grp << 2)]) = va;
            *reinterpret_cast<float4*>(&sB[pb ^ 1][row * BK + (grp << 2)]) = vb;
        }
        __syncthreads();
        compute(pb ^ 1);                      // zero-padded cols contribute 0
    }

    // epilogue: C/D layout col = lane&15, row = (lane>>4)*4 + reg  [m89/m91-verified]
    const int orow = (lane >> 4) * 4;
#pragma unroll
    for (int mi = 0; mi < 4; ++mi)
#pragma unroll
        for (int ni = 0; ni < 4; ++ni)
#pragma unroll
            for (int r2 = 0; r2 < 4; ++r2) {
                const int gm = bm0 + wm0 + mi * 16 + orow + r2;
                const int gn = bn0 + wn0 + ni * 16 + lm;
                atomicAdd(&emb[gm * EDIM + gn], acc[mi][ni][r2]);
            }
}

// Stage 2: per batch row b, out[b] = prod_l sigmoid( sign_l * <pv[b,l,:], emb[b,:]+bias> )
__global__ __launch_bounds__(256) void stage2_kernel(
    const float* __restrict__ emb, const float* __restrict__ bias,
    const float* __restrict__ pv, const int* __restrict__ signs,
    float* __restrict__ out) {
    const int b = blockIdx.x;
    __shared__ float se[EDIM];
    __shared__ float wp[4];
    const int t = threadIdx.x;
    se[t] = emb[b * EDIM + t] + bias[t];
    __syncthreads();
    const int w = t >> 6, lane = t & 63;
    float p = 1.0f;
    for (int l = w; l < LDIM; l += 4) {
        const float4 a = *reinterpret_cast<const float4*>(&pv[((size_t)b * LDIM + l) * EDIM + lane * 4]);
        const float4 e = *reinterpret_cast<const float4*>(&se[lane * 4]);
        float d = a.x * e.x + a.y * e.y + a.z * e.z + a.w * e.w;
#pragma unroll
        for (int off = 32; off > 0; off >>= 1) d += __shfl_xor(d, off, 64);
        const float zz = signs[b * LDIM + l] ? d : -d;
        p *= 1.0f / (1.0f + expf(-zz));
    }
    if (lane == 0) wp[w] = p;
    __syncthreads();
    if (t == 0) out[b] = wp[0] * wp[1] * wp[2] * wp[3];
}

extern "C" void kernel_launch(void* const* d_in, const int* in_sizes, int n_in,
                              void* d_out, int out_size, void* d_ws, size_t ws_size,
                              hipStream_t stream) {
    const float* X    = (const float*)d_in[0];   // [B, V]
    const float* Wm   = (const float*)d_in[1];   // [E, V]
    const float* bias = (const float*)d_in[2];   // [E]
    const float* pv   = (const float*)d_in[3];   // [B, L, E]
    const int*   sg   = (const int*)d_in[4];     // [B, L]
    float* out = (float*)d_out;                  // [B]
    float* emb = (float*)d_ws;                   // [B, E] fp32 accumulator (1 MB)

    hipMemsetAsync(emb, 0, (size_t)BDIM * EDIM * sizeof(float), stream);

    gemm_split3<<<dim3(NBLK), 256, 0, stream>>>(X, Wm, emb);

    stage2_kernel<<<BDIM, 256, 0, stream>>>(emb, bias, pv, sg, out);
}

// Round 2
// 380.271 us; speedup vs baseline: 1.0409x; 1.0409x over previous
//
#include <hip/hip_runtime.h>
#include <hip/hip_bf16.h>
#include <math.h>

// Problem constants (from reference)
#define VDIM 50000   // K (vocab / nodeNum)
#define BDIM 1024    // M (batch)
#define EDIM 256     // N (embedding)
#define LDIM 17      // Huffman path length

constexpr int BM = 128, BN = 128, BK = 32;
constexpr int KT_FULL = VDIM / BK;            // 1562 full k-tiles
constexpr int SPLITS  = 32;                   // interleaved split-K -> grid 512 = 2 blocks/CU
constexpr int TAILZ   = KT_FULL % SPLITS;     // 26: split owning the 16-col tail tile
constexpr int NBLK    = (EDIM / BN) * (BDIM / BM) * SPLITS;  // 512

typedef short bf16x8 __attribute__((ext_vector_type(8)));  // 8 bf16 (4 VGPRs)
typedef float f32x4  __attribute__((ext_vector_type(4)));

// async global->LDS, 16 B per lane; LDS dest = wave-uniform base + lane*16
__device__ __forceinline__ void async_f4(const float* g, float* l) {
    __builtin_amdgcn_global_load_lds(
        (const __attribute__((address_space(1))) void*)g,
        (__attribute__((address_space(3))) void*)l, 16, 0, 0);
}

// 8 consecutive fp32 -> bf16 hi fragment + bf16 lo fragment.
// hi = truncate(f); lo = truncate(f - hi); total error <= 2^-16 |f|.
__device__ __forceinline__ void split8(const float4 f0, const float4 f1, bf16x8& h, bf16x8& l) {
    const float f[8] = {f0.x, f0.y, f0.z, f0.w, f1.x, f1.y, f1.z, f1.w};
#pragma unroll
    for (int i = 0; i < 8; ++i) {
        const uint32_t u  = __float_as_uint(f[i]);
        h[i] = (short)(u >> 16);
        const float lo = f[i] - __uint_as_float(u & 0xFFFF0000u);
        l[i] = (short)(__float_as_uint(lo) >> 16);
    }
}

// emb_partial = x @ W^T, split-K. bf16 split-3 (Ah*Bh + Ah*Bl + Al*Bh).
// Double-buffered LDS pipeline; LDS holds raw fp32 tiles (global_load_lds,
// XOR-swizzled source columns; no padding allowed).
// 1-D grid + z-grouped XCD mapping: all 16 blocks of a split z share one XCD's L2.
//
// NEW (this round): epilogue writes per-split partial tiles with plain stores
// (part_mode) instead of 8.4M cross-XCD fp32 atomicAdds into one contended 1 MB
// accumulator; stage2 folds the 32-way z-reduction into its existing row load.
// Runtime-gated on ws_size >= 32 MB; atomic path kept as fallback.
__global__ __launch_bounds__(256) void gemm_split3(
    const float* __restrict__ X, const float* __restrict__ Wm,
    float* __restrict__ wsout, const int part) {
    __shared__ __align__(16) float sA[2][BM * BK];   // 2 x 16 KB
    __shared__ __align__(16) float sB[2][BN * BK];   // 2 x 16 KB

    const int tid = threadIdx.x;

    // XCD-grouped decode: n%8 = XCD (dispatch round-robin). Each XCD r owns
    // z in {4r .. 4r+3}; within a z, 16 blocks = 2 (E tiles) x 8 (B tiles).
    const int n   = blockIdx.x;
    const int r   = n & 7;
    const int q   = n >> 3;                   // 0..63
    const int z   = (r << 2) + (q >> 4);      // split: tiles z, z+SPLITS, ...
    const int t16 = q & 15;
    const int bn0 = (t16 & 1) * BN;           // E offset
    const int bm0 = (t16 >> 1) * BM;          // B offset

    const int lane = tid & 63;
    const int wv   = tid >> 6;                // wave 0..3
    const int wm0  = (wv >> 1) * 64;          // wave tile origin
    const int wn0  = (wv & 1) * 64;
    const int lm   = lane & 15;               // fragment m/n index
    const int gk0  = (lane >> 4) * 2;         // first 4-float group of this lane's k-slice

    // staging geometry: each wave-instruction deposits 8 rows x 32 floats (1 KB)
    const int rsub   = lane >> 3;             // row within 8-row chunk; == row&7
    const int grp    = lane & 7;              // LDS 4-float group this lane fills
    const int coloff = ((grp ^ rsub) << 2);   // swizzled source column within tile
    const int rowS   = wv * 32 + rsub;        // + j*8, j=0..3

    f32x4 acc[4][4] = {};

    auto issue = [&](int kt, int pb) {
        const int k0 = kt * BK;
#pragma unroll
        for (int j = 0; j < 4; ++j) {
            const int row = rowS + j * 8;
            async_f4(X  + (size_t)(bm0 + row) * VDIM + k0 + coloff, &sA[pb][(wv * 32 + j * 8) * BK]);
            async_f4(Wm + (size_t)(bn0 + row) * VDIM + k0 + coloff, &sB[pb][(wv * 32 + j * 8) * BK]);
        }
    };

    auto compute = [&](int pb) {
        const float* A = sA[pb];
        const float* Bs = sB[pb];
        bf16x8 ah[4], al[4];
#pragma unroll
        for (int mi = 0; mi < 4; ++mi) {
            const int row = wm0 + mi * 16 + lm;
            const int s = row & 7;
            const float4 f0 = *reinterpret_cast<const float4*>(&A[row * BK + ((gk0 ^ s) << 2)]);
            const float4 f1 = *reinterpret_cast<const float4*>(&A[row * BK + (((gk0 + 1) ^ s) << 2)]);
            split8(f0, f1, ah[mi], al[mi]);
        }
#pragma unroll
        for (int ni = 0; ni < 4; ++ni) {
            const int row = wn0 + ni * 16 + lm;
            const int s = row & 7;
            const float4 f0 = *reinterpret_cast<const float4*>(&Bs[row * BK + ((gk0 ^ s) << 2)]);
            const float4 f1 = *reinterpret_cast<const float4*>(&Bs[row * BK + (((gk0 + 1) ^ s) << 2)]);
            bf16x8 bh, bl;
            split8(f0, f1, bh, bl);
            // T5: favor the MFMA-entering wave over the co-resident block's VALU burst
            __builtin_amdgcn_s_setprio(1);
#pragma unroll
            for (int mi = 0; mi < 4; ++mi) {
                acc[mi][ni] = __builtin_amdgcn_mfma_f32_16x16x32_bf16(ah[mi], bh, acc[mi][ni], 0, 0, 0);
                acc[mi][ni] = __builtin_amdgcn_mfma_f32_16x16x32_bf16(ah[mi], bl, acc[mi][ni], 0, 0, 0);
                acc[mi][ni] = __builtin_amdgcn_mfma_f32_16x16x32_bf16(al[mi], bh, acc[mi][ni], 0, 0, 0);
            }
            __builtin_amdgcn_s_setprio(0);
        }
    };

    // pipelined main loop over this split's tiles
    int pb = 0;
    issue(z, 0);                              // prologue: first tile into buf 0
    for (int kt = z + SPLITS; kt < KT_FULL; kt += SPLITS) {
        __syncthreads();                      // drains vmcnt -> buf pb ready; buf pb^1 free
        issue(kt, pb ^ 1);                    // prefetch next tile (in flight across compute)
        compute(pb);
        pb ^= 1;
    }
    __syncthreads();                          // last tile's loads drained
    compute(pb);

    if (z == TAILZ) {                         // tail tile kt=1562: cols 49984..49999 valid
        const int k0 = KT_FULL * BK;
#pragma unroll
        for (int j = 0; j < 4; ++j) {
            const int row = rowS + j * 8;
            float4 va = make_float4(0.f, 0.f, 0.f, 0.f), vb = va;
            if (coloff < 16) {                // groups beyond K-remainder stay zero
                va = *reinterpret_cast<const float4*>(X  + (size_t)(bm0 + row) * VDIM + k0 + coloff);
                vb = *reinterpret_cast<const float4*>(Wm + (size_t)(bn0 + row) * VDIM + k0 + coloff);
            }
            // same LDS bytes the async path would write: base + lane*16
            *reinterpret_cast<float4*>(&sA[pb ^ 1][row * BK + (grp << 2)]) = va;
            *reinterpret_cast<float4*>(&sB[pb ^ 1][row * BK + (grp << 2)]) = vb;
        }
        __syncthreads();
        compute(pb ^ 1);                      // zero-padded cols contribute 0
    }

    // epilogue: C/D layout col = lane&15, row = (lane>>4)*4 + reg  [m89/m91-verified]
    const int orow = (lane >> 4) * 4;
    if (part) {
        // per-split partial tile, plain stores: ws[z][1024][256]; each element
        // written exactly once (blocks within a z tile the full [B,E] plane)
        float* dst = wsout + (size_t)z * BDIM * EDIM;
#pragma unroll
        for (int mi = 0; mi < 4; ++mi)
#pragma unroll
            for (int ni = 0; ni < 4; ++ni)
#pragma unroll
                for (int r2 = 0; r2 < 4; ++r2) {
                    const int gm = bm0 + wm0 + mi * 16 + orow + r2;
                    const int gn = bn0 + wn0 + ni * 16 + lm;
                    dst[(size_t)gm * EDIM + gn] = acc[mi][ni][r2];
                }
    } else {
#pragma unroll
        for (int mi = 0; mi < 4; ++mi)
#pragma unroll
            for (int ni = 0; ni < 4; ++ni)
#pragma unroll
                for (int r2 = 0; r2 < 4; ++r2) {
                    const int gm = bm0 + wm0 + mi * 16 + orow + r2;
                    const int gn = bn0 + wn0 + ni * 16 + lm;
                    atomicAdd(&wsout[gm * EDIM + gn], acc[mi][ni][r2]);
                }
    }
}

// Stage 2: per batch row b, out[b] = prod_l sigmoid( sign_l * <pv[b,l,:], emb[b,:]+bias> )
// part mode: emb row b is materialized here as sum over the 32 split partials
// (32 KB of LLC-hot, fully-coalesced loads per block) -- replaces the atomics.
__global__ __launch_bounds__(256) void stage2_kernel(
    const float* __restrict__ ws, const float* __restrict__ bias,
    const float* __restrict__ pv, const int* __restrict__ signs,
    float* __restrict__ out, const int part) {
    const int b = blockIdx.x;
    __shared__ float se[EDIM];
    __shared__ float wp[4];
    const int t = threadIdx.x;
    float s = bias[t];
    if (part) {
#pragma unroll
        for (int zz = 0; zz < SPLITS; ++zz)
            s += ws[((size_t)zz * BDIM + b) * EDIM + t];
    } else {
        s += ws[b * EDIM + t];
    }
    se[t] = s;
    __syncthreads();
    const int w = t >> 6, lane = t & 63;
    float p = 1.0f;
    for (int l = w; l < LDIM; l += 4) {
        const float4 a = *reinterpret_cast<const float4*>(&pv[((size_t)b * LDIM + l) * EDIM + lane * 4]);
        const float4 e = *reinterpret_cast<const float4*>(&se[lane * 4]);
        float d = a.x * e.x + a.y * e.y + a.z * e.z + a.w * e.w;
#pragma unroll
        for (int off = 32; off > 0; off >>= 1) d += __shfl_xor(d, off, 64);
        const float zz = signs[b * LDIM + l] ? d : -d;
        p *= 1.0f / (1.0f + expf(-zz));
    }
    if (lane == 0) wp[w] = p;
    __syncthreads();
    if (t == 0) out[b] = wp[0] * wp[1] * wp[2] * wp[3];
}

extern "C" void kernel_launch(void* const* d_in, const int* in_sizes, int n_in,
                              void* d_out, int out_size, void* d_ws, size_t ws_size,
                              hipStream_t stream) {
    const float* X    = (const float*)d_in[0];   // [B, V]
    const float* Wm   = (const float*)d_in[1];   // [E, V]
    const float* bias = (const float*)d_in[2];   // [E]
    const float* pv   = (const float*)d_in[3];   // [B, L, E]
    const int*   sg   = (const int*)d_in[4];     // [B, L]
    float* out = (float*)d_out;                  // [B]
    float* ws  = (float*)d_ws;

    const size_t need = (size_t)SPLITS * BDIM * EDIM * sizeof(float);  // 32 MB
    const int part = (ws_size >= need) ? 1 : 0;

    if (!part)  // atomic fallback needs a zeroed 1 MB accumulator
        hipMemsetAsync(ws, 0, (size_t)BDIM * EDIM * sizeof(float), stream);

    gemm_split3<<<dim3(NBLK), 256, 0, stream>>>(X, Wm, ws, part);

    stage2_kernel<<<BDIM, 256, 0, stream>>>(ws, bias, pv, sg, out, part);
}